// Round 10
// baseline (449.088 us; speedup 1.0000x reference)
//
#include <hip/hip_runtime.h>

#define NN 50000
#define MP 50048   // padded to 391*128
#define NH 4
#define NR 6
#define NE 300000
#define HD 256     // NH*DHD
#define SLOTS 32   // max degree per (relation,node); P(deg>32) ~ 1e-14
#define NB 512
#define BSZ ((NE + NB - 1) / NB)  // 586
#define GEMM_BLKS (391 * 2 * NR)  // 4692
#define ELER_BLKS 391

typedef __attribute__((ext_vector_type(4))) float f32x4;
typedef __attribute__((ext_vector_type(8))) short bf16x8;

__device__ __forceinline__ short f2bf(float f) {
  unsigned u = __float_as_uint(f);
  unsigned r = (u + 0x7FFFu + ((u >> 16) & 1u)) >> 16;  // round-nearest-even
  return (short)r;
}
__device__ __forceinline__ float bf2f_lo(unsigned d) {
  return __uint_as_float(d << 16);
}
__device__ __forceinline__ float bf2f_hi(unsigned d) {
  return __uint_as_float(d & 0xffff0000u);
}

#define GLOAD_LDS16(g, l)                                                     \
  __builtin_amdgcn_global_load_lds(                                           \
      (const __attribute__((address_space(1))) void*)(g),                     \
      (__attribute__((address_space(3))) void*)(l), 16, 0, 0)

// ---------------- prep_fast: cast_x | cast_wt | wlwr ----------------------
// Only the cheap transforms gemm/eler depend on. Build moves to mid_kernel
// (it has no consumers until agg, so it can hide under gemm).
// blocks [0,512): cast_x; [512,896): cast_wt; [896,1024): wlwr.
__global__ __launch_bounds__(256) void prep_fast_kernel(
    const float* __restrict__ x, short* __restrict__ xb,
    const float* __restrict__ W, short* __restrict__ wt,
    const float* __restrict__ attn_l, const float* __restrict__ attn_r,
    short* __restrict__ wlwr) {
  __shared__ float ts[32][33];
  const int bid = blockIdx.x;
  const int t = threadIdx.x;

  if (bid < 512) {
    // ---- cast_x: x (f32) -> xb (bf16), 3.2M float4, grid-stride ----
    for (int i = bid * 256 + t; i < NN * HD / 4; i += 512 * 256) {
      const float4 v = ((const float4*)x)[i];
      short4 o;
      o.x = f2bf(v.x); o.y = f2bf(v.y); o.z = f2bf(v.z); o.w = f2bf(v.w);
      ((short4*)xb)[i] = o;
    }
  } else if (bid < 896) {
    // ---- cast_wt: LDS 32x32 tile transpose, coalesced both sides ----
    const int bx = bid - 512;           // r * 64 + tile
    const int r = bx >> 6;
    const int tile = bx & 63;
    const int k0 = (tile >> 3) * 32;
    const int n0 = (tile & 7) * 32;
    const int col = t & 31;
    const int rr = t >> 5;  // 8 rows per pass
#pragma unroll
    for (int p = 0; p < 4; ++p) {
      const int row = p * 8 + rr;
      ts[row][col] = W[(size_t)r * 65536 + (k0 + row) * 256 + n0 + col];
    }
    __syncthreads();
#pragma unroll
    for (int p = 0; p < 4; ++p) {
      const int row = p * 8 + rr;  // n index
      wt[(size_t)r * 65536 + (n0 + row) * 256 + k0 + col] =
          f2bf(ts[col][row]);
    }
  } else {
    // ---- wlwr[n][k]: fused attn-projection (exact sum swap, R6) ----
    const int idx = (bid - 896) * 256 + t;  // over 128*256
    const int k = idx & 255;
    const int n = idx >> 8;
    float v = 0.f;
    if (n < 48) {
      const int r = n >> 3, h = (n >> 1) & 3, side = n & 1;
      const float* a = (side ? attn_r : attn_l) + r * 256 + h * 64;
      const float* wrow = W + (size_t)r * 65536 + (size_t)k * 256 + h * 64;
#pragma unroll 8
      for (int dh = 0; dh < 64; ++dh) v = fmaf(wrow[dh], a[dh], v);
    }
    wlwr[(size_t)n * 256 + k] = f2bf(v);
  }
}

// ---------------- mid: build || gemm || eler (one launch) -----------------
// R9 reveal: prep=106us at 1.9% VALU -- build's random u16 scatter (135MB
// write-back, ~3x amplification across 8 non-coherent L2s) ran SERIAL
// before gemm while needing no gemm input. Here build blocks [0,512) are
// first in the grid (dispatch first), gemm [512,5204) and eler
// [5204,5595) follow; stream order still puts all of it before agg.
// Branch bodies byte-identical to R6/R9-verified kernels.
__global__ __launch_bounds__(256) void mid_kernel(
    const int* __restrict__ src, const int* __restrict__ dst,
    int* __restrict__ deg, unsigned short* __restrict__ slots,
    const short* __restrict__ xb, const short* __restrict__ wt_all,
    short* __restrict__ featb_all, const short* __restrict__ wlwr,
    float* __restrict__ el_all, float* __restrict__ er_all) {
  __shared__ short As[128 * 64];
  __shared__ short Bs[128 * 64];
  const int bid = blockIdx.x;
  const int t = threadIdx.x;

  if (bid < NB) {
    // ---- build: single-pass fixed-slot buckets (R6-verified) ----
    const int lo = bid * BSZ;
    const int hi = (lo + BSZ < NE) ? lo + BSZ : NE;
    for (int r = 0; r < NR; ++r) {
      for (int i = lo + t; i < hi; i += 256) {
        const int s = src[(size_t)r * NE + i];
        const int d = dst[(size_t)r * NE + i];
        const int g = r * NN + d;
        const int sl = atomicAdd(&deg[g], 1);
        if (sl < SLOTS)
          slots[(size_t)g * SLOTS + sl] = (unsigned short)s;
      }
    }
    return;
  }

  const int lane = t & 63;
  const int w = t >> 6;
  const int wm = w & 1, wn = w >> 1;
  const int ra = lane & 15;
  const int qg = lane >> 4;

  if (bid < NB + GEMM_BLKS) {
    // ---- gemm: R6-verified BK=64 swizzled, decode preserves
    //      391-block runs of constant (n0, r) for B-tile L2 reuse ----
    const int id = bid - NB;
    const int r = id / 782;
    const int rem = id - r * 782;
    const int n0 = (rem / 391) << 7;
    const int row0 = (rem % 391) << 7;
    const short* wt = wt_all + (size_t)r * 65536;
    short* featb = featb_all + (size_t)r * MP * 256;

    f32x4 acc[4][4];
#pragma unroll
    for (int mi = 0; mi < 4; ++mi)
#pragma unroll
      for (int ni = 0; ni < 4; ++ni) {
        f32x4 z = {0.f, 0.f, 0.f, 0.f};
        acc[mi][ni] = z;
      }

    const short* ag[4];
    const short* bg[4];
    short* la[4];
    short* lb[4];
#pragma unroll
    for (int i = 0; i < 4; ++i) {
      const int c = t + 256 * i;
      const int row = c >> 3;
      const int sslot = (c & 7) ^ (row & 7);
      int ar = row0 + row; if (ar >= NN) ar = NN - 1;
      ag[i] = xb + (size_t)ar * 256 + sslot * 8;
      bg[i] = wt + (size_t)(n0 + row) * 256 + sslot * 8;
      la[i] = As + c * 8;
      lb[i] = Bs + c * 8;
    }

    for (int k0 = 0; k0 < 256; k0 += 64) {
#pragma unroll
      for (int i = 0; i < 4; ++i) {
        GLOAD_LDS16(ag[i] + k0, la[i]);
        GLOAD_LDS16(bg[i] + k0, lb[i]);
      }
      __syncthreads();
#pragma unroll
      for (int kk = 0; kk < 2; ++kk) {
        bf16x8 af[4], bfr[4];
#pragma unroll
        for (int mi = 0; mi < 4; ++mi) {
          const int rw = wm * 64 + mi * 16 + ra;
          const int ch = (kk * 4 + qg) ^ (rw & 7);
          af[mi] = *(const bf16x8*)&As[rw * 64 + ch * 8];
        }
#pragma unroll
        for (int ni = 0; ni < 4; ++ni) {
          const int rw = wn * 64 + ni * 16 + ra;
          const int ch = (kk * 4 + qg) ^ (rw & 7);
          bfr[ni] = *(const bf16x8*)&Bs[rw * 64 + ch * 8];
        }
#pragma unroll
        for (int mi = 0; mi < 4; ++mi)
#pragma unroll
          for (int ni = 0; ni < 4; ++ni)
            acc[mi][ni] = __builtin_amdgcn_mfma_f32_16x16x32_bf16(
                af[mi], bfr[ni], acc[mi][ni], 0, 0, 0);
      }
      __syncthreads();
    }

#pragma unroll
    for (int mi = 0; mi < 4; ++mi) {
#pragma unroll
      for (int j = 0; j < 4; ++j) {
        const int row = row0 + wm * 64 + mi * 16 + qg * 4 + j;
#pragma unroll
        for (int ni = 0; ni < 4; ++ni)
          featb[(size_t)row * 256 + n0 + wn * 64 + ni * 16 + ra] =
              f2bf(acc[mi][ni][j]);
      }
    }
    return;
  }

  // ---- eler: skinny xb @ wlwr^T (R6-verified) ----
  {
    const int row0 = (bid - NB - GEMM_BLKS) << 7;

    f32x4 acc[4][4];
#pragma unroll
    for (int mi = 0; mi < 4; ++mi)
#pragma unroll
      for (int ni = 0; ni < 4; ++ni) {
        f32x4 z = {0.f, 0.f, 0.f, 0.f};
        acc[mi][ni] = z;
      }

    const short* ag[4];
    const short* bg[4];
    short* la[4];
    short* lb[4];
#pragma unroll
    for (int i = 0; i < 4; ++i) {
      const int c = t + 256 * i;
      const int row = c >> 3;
      const int sslot = (c & 7) ^ (row & 7);
      int ar = row0 + row; if (ar >= NN) ar = NN - 1;
      ag[i] = xb + (size_t)ar * 256 + sslot * 8;
      bg[i] = wlwr + (size_t)row * 256 + sslot * 8;
      la[i] = As + c * 8;
      lb[i] = Bs + c * 8;
    }

    for (int k0 = 0; k0 < 256; k0 += 64) {
#pragma unroll
      for (int i = 0; i < 4; ++i) {
        GLOAD_LDS16(ag[i] + k0, la[i]);
        GLOAD_LDS16(bg[i] + k0, lb[i]);
      }
      __syncthreads();
#pragma unroll
      for (int kk = 0; kk < 2; ++kk) {
        bf16x8 af[4], bfr[4];
#pragma unroll
        for (int mi = 0; mi < 4; ++mi) {
          const int rw = wm * 64 + mi * 16 + ra;
          const int ch = (kk * 4 + qg) ^ (rw & 7);
          af[mi] = *(const bf16x8*)&As[rw * 64 + ch * 8];
        }
#pragma unroll
        for (int ni = 0; ni < 4; ++ni) {
          const int rw = wn * 64 + ni * 16 + ra;
          const int ch = (kk * 4 + qg) ^ (rw & 7);
          bfr[ni] = *(const bf16x8*)&Bs[rw * 64 + ch * 8];
        }
#pragma unroll
        for (int mi = 0; mi < 4; ++mi)
#pragma unroll
          for (int ni = 0; ni < 4; ++ni)
            acc[mi][ni] = __builtin_amdgcn_mfma_f32_16x16x32_bf16(
                af[mi], bfr[ni], acc[mi][ni], 0, 0, 0);
      }
      __syncthreads();
    }

#pragma unroll
    for (int mi = 0; mi < 4; ++mi) {
#pragma unroll
      for (int j = 0; j < 4; ++j) {
        const int row = row0 + wm * 64 + mi * 16 + qg * 4 + j;
        if (row >= NN) continue;
#pragma unroll
        for (int ni = 0; ni < 4; ++ni) {
          const int c = wn * 64 + ni * 16 + ra;
          if (c < 48) {
            const int r = c >> 3, h = (c >> 1) & 3, side = c & 1;
            float* dstp = (side ? er_all : el_all);
            dstp[((size_t)r * NN + row) * NH + h] = acc[mi][ni][j];
          }
        }
      }
    }
  }
}

// ---------------- fused all-relation aggregation, SGPR slot list ----------
// CONTROL math (R6-verified, random-gather BW-bound). Two half-node
// launches (R9 profiling-reveal split retained).
__global__ __launch_bounds__(256) void agg_kernel(
    const short* __restrict__ featb_all, const float* __restrict__ el_all,
    const float* __restrict__ er_all, const int* __restrict__ deg,
    const unsigned short* __restrict__ slots, const float* __restrict__ bias,
    float* __restrict__ out, int base) {
  const int wid = base + ((blockIdx.x * 256 + threadIdx.x) >> 6);
  const int lane = threadIdx.x & 63;
  if (wid >= NN) return;
  const int h = lane >> 4;   // 16 lanes per head (64 cols / 4 per lane)
  const int c0 = lane * 4;   // this lane's 4 columns

  float oacc[4] = {0.f, 0.f, 0.f, 0.f};
  const int wid_u = __builtin_amdgcn_readfirstlane(wid);

  const int g_first = (NR - 1) * NN + wid_u;
  const uint4* spf = (const uint4*)(slots + (size_t)g_first * SLOTS);
  uint4 sq0 = spf[0], sq1 = spf[1], sq2 = spf[2], sq3 = spf[3];
  int dgv = deg[g_first];
  float erv = er_all[(size_t)g_first * NH + h];

  for (int r = NR - 1; r >= 0; --r) {
    const int dg0 = __builtin_amdgcn_readfirstlane(dgv);
    const int dg = dg0 > SLOTS ? SLOTS : dg0;
    unsigned sdv[16];
    sdv[0]  = __builtin_amdgcn_readfirstlane(sq0.x);
    sdv[1]  = __builtin_amdgcn_readfirstlane(sq0.y);
    sdv[2]  = __builtin_amdgcn_readfirstlane(sq0.z);
    sdv[3]  = __builtin_amdgcn_readfirstlane(sq0.w);
    sdv[4]  = __builtin_amdgcn_readfirstlane(sq1.x);
    sdv[5]  = __builtin_amdgcn_readfirstlane(sq1.y);
    sdv[6]  = __builtin_amdgcn_readfirstlane(sq1.z);
    sdv[7]  = __builtin_amdgcn_readfirstlane(sq1.w);
    sdv[8]  = __builtin_amdgcn_readfirstlane(sq2.x);
    sdv[9]  = __builtin_amdgcn_readfirstlane(sq2.y);
    sdv[10] = __builtin_amdgcn_readfirstlane(sq2.z);
    sdv[11] = __builtin_amdgcn_readfirstlane(sq2.w);
    sdv[12] = __builtin_amdgcn_readfirstlane(sq3.x);
    sdv[13] = __builtin_amdgcn_readfirstlane(sq3.y);
    sdv[14] = __builtin_amdgcn_readfirstlane(sq3.z);
    sdv[15] = __builtin_amdgcn_readfirstlane(sq3.w);
    const float er_nh = erv;

    if (r > 0) {
      const int g2 = (r - 1) * NN + wid_u;
      const uint4* sp2 = (const uint4*)(slots + (size_t)g2 * SLOTS);
      sq0 = sp2[0]; sq1 = sp2[1]; sq2 = sp2[2]; sq3 = sp2[3];
      dgv = deg[g2];
      erv = er_all[(size_t)g2 * NH + h];
    }

    const float* elr = el_all + (size_t)r * NN * NH;
    const short* fb = featb_all + (size_t)r * MP * 256;

    float z = 0.f;
    float acc[4] = {0.f, 0.f, 0.f, 0.f};

#pragma unroll
    for (int j0 = 0; j0 < SLOTS; j0 += 8) {
      if (j0 >= dg) break;  // uniform (dg is SGPR)
      float pv[8];
      uint2 rw[8];
#pragma unroll
      for (int k = 0; k < 8; ++k) {
        const int e = j0 + k;  // compile-time after unroll
        int s = (int)((e & 1) ? (sdv[e >> 1] >> 16) : (sdv[e >> 1] & 0xffffu));
        const bool v = e < dg;           // uniform
        s = v ? s : 0;                   // row 0 stays hot
        rw[k] = *(const uint2*)(fb + (size_t)s * 256 + c0);  // SGPR base+voff
        float ev = elr[s * NH + h] + er_nh;
        ev = fmaxf(ev, 0.2f * ev);       // leaky_relu(0.2)
        pv[k] = v ? __expf(ev) : 0.f;
      }
#pragma unroll
      for (int k = 0; k < 8; ++k) {
        z += pv[k];
        acc[0] = fmaf(pv[k], bf2f_lo(rw[k].x), acc[0]);
        acc[1] = fmaf(pv[k], bf2f_hi(rw[k].x), acc[1]);
        acc[2] = fmaf(pv[k], bf2f_lo(rw[k].y), acc[2]);
        acc[3] = fmaf(pv[k], bf2f_hi(rw[k].y), acc[3]);
      }
    }

    const float inv = 1.f / fmaxf(z, 1e-9f);
    const float4 bv = *(const float4*)(bias + r * HD + c0);
    oacc[0] += fmaxf(fmaf(acc[0], inv, bv.x), 0.f);
    oacc[1] += fmaxf(fmaf(acc[1], inv, bv.y), 0.f);
    oacc[2] += fmaxf(fmaf(acc[2], inv, bv.z), 0.f);
    oacc[3] += fmaxf(fmaf(acc[3], inv, bv.w), 0.f);
  }

  float4 o4 = {oacc[0], oacc[1], oacc[2], oacc[3]};
  *(float4*)(out + (size_t)wid * 256 + c0) = o4;  // full-wave 1KB store
}

// ---------------------------------------------------------------------------
extern "C" void kernel_launch(void* const* d_in, const int* in_sizes, int n_in,
                              void* d_out, int out_size, void* d_ws,
                              size_t ws_size, hipStream_t stream) {
  const float* x      = (const float*)d_in[0];
  const float* W      = (const float*)d_in[1];
  const float* attn_l = (const float*)d_in[2];
  const float* attn_r = (const float*)d_in[3];
  const float* bias   = (const float*)d_in[4];
  const int*   src    = (const int*)d_in[5];   // int32 per harness contract
  const int*   dst    = (const int*)d_in[6];
  float* out = (float*)d_out;

  char* p = (char*)d_ws;
  auto alloc = [&](size_t bytes) {
    char* r = p;
    p += (bytes + 255) & ~(size_t)255;
    return r;
  };
  short* xb    = (short*)alloc((size_t)NN * HD * 2);            // 25.6 MB
  short* wt    = (short*)alloc((size_t)NR * 256 * 256 * 2);     // 0.79 MB
  short* wlwr  = (short*)alloc((size_t)128 * 256 * 2);          // 64 KB
  short* featb = (short*)alloc((size_t)NR * MP * 256 * 2);      // 153.7 MB
  float* el    = (float*)alloc((size_t)NR * NN * NH * 4);       // 4.8 MB
  float* er    = (float*)alloc((size_t)NR * NN * NH * 4);       // 4.8 MB
  int*   deg   = (int*)alloc((size_t)NR * NN * 4);              // 1.2 MB
  unsigned short* slots =
      (unsigned short*)alloc((size_t)NR * NN * SLOTS * 2);      // 19.2 MB

  hipMemsetAsync(deg, 0, (size_t)NR * NN * 4, stream);

  prep_fast_kernel<<<1024, 256, 0, stream>>>(x, xb, W, wt, attn_l, attn_r,
                                             wlwr);
  mid_kernel<<<NB + GEMM_BLKS + ELER_BLKS, 256, 0, stream>>>(
      src, dst, deg, slots, xb, wt, featb, wlwr, el, er);
  agg_kernel<<<6250, 256, 0, stream>>>(featb, el, er, deg, slots, bias, out,
                                       0);
  agg_kernel<<<6250, 256, 0, stream>>>(featb, el, er, deg, slots, bias, out,
                                       25000);
}